// Round 9
// baseline (461.468 us; speedup 1.0000x reference)
//
#include <hip/hip_runtime.h>
#include <hip/hip_bf16.h>
#include <hip/hip_cooperative_groups.h>
#include <math.h>

namespace cg = cooperative_groups;

#define Bsz 64
#define T 32
#define H 768
#define E 8
#define NB 2
#define DFF 3072
#define NBEAM (Bsz * NB)   // 128
#define NT8MAX 24
#define NBLK 576

// d_out layout (floats):
#define OUT_BS 3145728
#define OUT_ER 3145856
#define OUT_BI 3145984
#define OUT_IL 3146112

// ws layout (float units):
#define WS_LOGITS 0
#define WS_BEAMW  1536
#define WS_SORT   1664
#define WS_T8E    1792
#define WS_T8B    1832
#define WS_T8C    1872
#define WS_XBF    2048
#define WS_HBF    (2048 + 786432)

typedef __attribute__((ext_vector_type(8))) short short8;
typedef __attribute__((ext_vector_type(4))) float f32x4;

__device__ __forceinline__ short8 cvt8(const float4 u, const float4 v) {
    union { short8 s; unsigned w[4]; } r;
    __hip_bfloat162 t;
    t = __float22bfloat162_rn(make_float2(u.x, u.y)); r.w[0] = *(unsigned*)&t;
    t = __float22bfloat162_rn(make_float2(u.z, u.w)); r.w[1] = *(unsigned*)&t;
    t = __float22bfloat162_rn(make_float2(v.x, v.y)); r.w[2] = *(unsigned*)&t;
    t = __float22bfloat162_rn(make_float2(v.z, v.w)); r.w[3] = *(unsigned*)&t;
    return r.s;
}

__device__ __forceinline__ void async16(void* lds, const void* g) {
    __builtin_amdgcn_global_load_lds(
        (const __attribute__((address_space(1))) void*)g,
        (__attribute__((address_space(3))) void*)lds, 16, 0, 0);
}

// ---------------------------------------------------------------------------
// Shared GEMM body (R5-proven loop: 2-buffer, one __syncthreads per k-tile,
// 0-conflict swizzle). Tables/beamw via generic pointers (LDS in fused path,
// global in fallback). NTILE fixed at 128.
// ---------------------------------------------------------------------------
template <int KTOT, bool DO_GELU, int NSLICE, int NX>
__device__ __forceinline__ void gemm_body(
    int hw,
    const ushort* __restrict__ Abf, int a_div,
    const float* __restrict__ Wf32, int w_rows,
    const float* __restrict__ biasb,
    const int* sortb, const int* t8e, const int* t8b, const int* t8c,
    const float* beamw, void* __restrict__ Obase,
    ushort (*sA)[256 * 32], ushort (*sB)[128 * 32])
{
    constexpr int KSPAN = KTOT / NSLICE;
    constexpr int KT    = KSPAN / 32;
    constexpr int NFRAG = 4;
    constexpr int WSLOT = 2;

    const int q8  = NBLK >> 3;                 // 72
    const int lid = (hw & 7) * q8 + (hw >> 3); // bijective on [0,576)
    const int tile  = lid % NT8MAX;
    const int rr    = lid / NT8MAX;
    const int strip = rr % NX;
    const int k0    = (rr / NX) * KSPAN;

    const int cnt  = t8c[tile];
    if (cnt == 0) return;
    const int e    = t8e[tile];
    const int base = t8b[tile];
    const int tid  = threadIdx.x;
    const int wv   = tid >> 6;
    const int lane = tid & 63;
    const int quad = lane >> 4;
    const int l16  = lane & 15;
    const int mh   = (wv & 1) * 128;
    const int nh   = (wv >> 1) * 64;
    const int n0   = strip * 128;

    int bm[8];
    #pragma unroll
    for (int s = 0; s < 8; ++s) bm[s] = sortb[base + (s < cnt ? s : cnt - 1)];

    const ushort* aseg[4];
    #pragma unroll
    for (int jj = 0; jj < 4; ++jj) {
        const int s = (wv * 4 + jj) * 64 + lane;
        const int r = s >> 2;
        const int c = (s & 3) ^ ((s >> 3) & 3);
        aseg[jj] = Abf + (size_t)(bm[r >> 5] / a_div) * T * KTOT
                 + (size_t)(r & 31) * KTOT + c * 8 + k0;
    }
    const float* wseg[WSLOT];
    int wslot[WSLOT];
    #pragma unroll
    for (int jj = 0; jj < WSLOT; ++jj) {
        const int s = jj * 256 + tid;
        const int r = s >> 2;
        const int c = (s & 3) ^ ((s >> 3) & 3);
        wseg[jj] = Wf32 + (size_t)e * w_rows * KTOT + (size_t)(n0 + r) * KTOT
                 + c * 8 + k0;
        wslot[jj] = s * 8;
    }

    const int fx = (l16 >> 1) & 3;
    int aoff[8], boff[NFRAG];
    #pragma unroll
    for (int mt = 0; mt < 8; ++mt)
        aoff[mt] = (mh + mt * 16 + l16) * 32 + ((quad ^ fx) * 8);
    #pragma unroll
    for (int nt = 0; nt < NFRAG; ++nt)
        boff[nt] = (nh + nt * 16 + l16) * 32 + ((quad ^ fx) * 8);

    float4 wr[WSLOT][2];
    #pragma unroll
    for (int jj = 0; jj < WSLOT; ++jj) {
        wr[jj][0] = *(const float4*)(wseg[jj]);
        wr[jj][1] = *(const float4*)(wseg[jj] + 4);
    }
    #pragma unroll
    for (int jj = 0; jj < 4; ++jj)
        async16((char*)sA[0] + (wv * 4 + jj) * 1024, aseg[jj]);

    f32x4 acc[8][NFRAG];
    #pragma unroll
    for (int mt = 0; mt < 8; ++mt)
        #pragma unroll
        for (int nt = 0; nt < NFRAG; ++nt) acc[mt][nt] = {0.f, 0.f, 0.f, 0.f};

    for (int kt = 0; kt < KT; ++kt) {
        const int p = kt & 1;
        #pragma unroll
        for (int jj = 0; jj < WSLOT; ++jj)
            *(short8*)(sB[p] + wslot[jj]) = cvt8(wr[jj][0], wr[jj][1]);
        __syncthreads();
        if (kt + 1 < KT) {
            const int kn = (kt + 1) * 32;
            #pragma unroll
            for (int jj = 0; jj < 4; ++jj)
                async16((char*)sA[1 - p] + (wv * 4 + jj) * 1024, aseg[jj] + kn);
            #pragma unroll
            for (int jj = 0; jj < WSLOT; ++jj) {
                wr[jj][0] = *(const float4*)(wseg[jj] + kn);
                wr[jj][1] = *(const float4*)(wseg[jj] + kn + 4);
            }
        }
        short8 wf[NFRAG];
        #pragma unroll
        for (int nt = 0; nt < NFRAG; ++nt)
            wf[nt] = *(const short8*)(sB[p] + boff[nt]);
        #pragma unroll
        for (int mt = 0; mt < 8; ++mt) {
            const short8 af = *(const short8*)(sA[p] + aoff[mt]);
            #pragma unroll
            for (int nt = 0; nt < NFRAG; ++nt)
                acc[mt][nt] = __builtin_amdgcn_mfma_f32_16x16x32_bf16(
                    af, wf[nt], acc[mt][nt], 0, 0, 0);
        }
    }
    __syncthreads();   // all reads of sA/sB done before caller reuses LDS

    #pragma unroll
    for (int nt = 0; nt < NFRAG; ++nt) {
        const int n = n0 + nh + nt * 16 + l16;
        const float bias = biasb[(size_t)e * w_rows + n];
        #pragma unroll
        for (int mt = 0; mt < 8; ++mt) {
            const int rowb = mh + mt * 16 + quad * 4;
            const int s = rowb >> 5;
            if (s >= cnt) continue;
            const int b = bm[s];
            const float scale = DO_GELU ? 1.0f : beamw[b];
            #pragma unroll
            for (int r = 0; r < 4; ++r) {
                const int t = (rowb + r) & 31;
                const size_t idx = (size_t)b * T * w_rows + (size_t)t * w_rows + n;
                if (DO_GELU) {
                    float vv = acc[mt][nt][r] + bias;
                    vv = 0.5f * vv * (1.0f + erff(vv * 0.70710678118654752f));
                    ((__hip_bfloat16*)Obase)[idx] = __float2bfloat16(vv);
                } else {
                    float vv = acc[mt][nt][r] + ((k0 == 0) ? bias : 0.f);
                    atomicAdd((float*)Obase + idx, vv * scale);
                }
            }
        }
    }
}

// ---------------------------------------------------------------------------
// FUSED cooperative kernel (round-9): the 5-dispatch train collapsed to one.
// Evidence: GEMM1 and GEMM2 take the SAME ~90us in every round despite 4x
// different K-iters / different epilogues / different W formats (R0-R8), all
// pipes <18% busy, and wall time exceeds sum-of-dispatches by ~100us ->
// per-dispatch ramp/drain+gap overhead is the remaining unfalsified binder.
// Phases: P0 zero-out + gate/conv | gsync | P1 gating (redundant per-block
// into LDS -- no cross-block table coherence needed) + P2 GEMM1 | gsync |
// P3 GEMM2 (split-K=4, atomics).
// LDS 50.5KB -> 3 blocks/CU -> 768 >= 576 co-resident. launch_bounds(256,3)
// caps VGPR at 170 so co-residency is guaranteed.
// ---------------------------------------------------------------------------
__global__ __launch_bounds__(256, 3) void fused_moe(
    const float* __restrict__ x, const float* __restrict__ gate_w,
    const float* __restrict__ w1, const float* __restrict__ b1,
    const float* __restrict__ w2, const float* __restrict__ b2,
    float* __restrict__ out, ushort* __restrict__ x_bf,
    ushort* __restrict__ h_bf, float* __restrict__ logits)
{
    __shared__ __align__(16) ushort sA[2][256 * 32];   // 32 KB
    __shared__ __align__(16) ushort sB[2][128 * 32];   // 16 KB
    __shared__ float ls_part[4][E];
    __shared__ float ls_beamw[NBEAM];
    __shared__ int   ls_sortb[NBEAM];
    __shared__ int   ls_t8e[NT8MAX], ls_t8b[NT8MAX], ls_t8c[NT8MAX];

    const int hw  = blockIdx.x;
    const int tid = threadIdx.x;
    cg::grid_group grid = cg::this_grid();

    // ---- Phase 0a: zero the atomic output region (3,145,728 floats) ----
    {
        float4 z = {0.f, 0.f, 0.f, 0.f};
        for (int i = hw * 256 + tid; i < (NBEAM * T * H / 4); i += NBLK * 256)
            ((float4*)out)[i] = z;
    }
    // ---- Phase 0b: gate partials + x fp32->bf16 (192 blocks) ----
    if (hw < 192) {
        const int chunk = hw % 3, b = hw / 3;
        const int wv = tid >> 6, lane = tid & 63;
        const int c = chunk * 256 + tid;
        const float* xp = x + (size_t)b * T * H + c;
        ushort* xo = x_bf + (size_t)b * T * H + c;
        float s = 0.f;
        #pragma unroll
        for (int t = 0; t < T; t += 2) {
            const float f0 = xp[t * H];
            const float f1 = xp[(t + 1) * H];
            s += f0; s += f1;
            __hip_bfloat162 t2 = __float22bfloat162_rn(make_float2(f0, f1));
            const unsigned u = *(const unsigned*)&t2;
            xo[t * H]       = (ushort)(u & 0xffff);
            xo[(t + 1) * H] = (ushort)(u >> 16);
        }
        const float avg = s * (1.0f / T);
        #pragma unroll
        for (int e = 0; e < E; ++e) {
            float p = avg * gate_w[e * H + c];
            #pragma unroll
            for (int off = 32; off; off >>= 1) p += __shfl_down(p, off, 64);
            if (lane == 0) ls_part[wv][e] = p;
        }
        __syncthreads();
        if (tid < E) {
            float t = ls_part[0][tid] + ls_part[1][tid]
                    + ls_part[2][tid] + ls_part[3][tid];
            logits[chunk * 512 + b * E + tid] = t;
        }
    }

    grid.sync();   // logits + x_bf + zeroed out visible everywhere

    // ---- Phase 1: gating, computed redundantly by EVERY block's wave 0 ----
    if (tid < 64) {
        const int r = tid;
        float v[E];
        float mx = -1e30f;
        #pragma unroll
        for (int e = 0; e < E; ++e) {
            v[e] = logits[r * E + e] + logits[512 + r * E + e]
                 + logits[1024 + r * E + e];
            mx = fmaxf(mx, v[e]);
        }
        float s = 0.f;
        #pragma unroll
        for (int e = 0; e < E; ++e) { v[e] = expf(v[e] - mx); s += v[e]; }
        const float inv = 1.0f / s;
        #pragma unroll
        for (int e = 0; e < E; ++e) v[e] *= inv;
        float v0 = -1.f, v1 = -1.f; int i0 = 0, i1 = 0;
        #pragma unroll
        for (int e = 0; e < E; ++e) {
            if (v[e] > v0)      { v1 = v0; i1 = i0; v0 = v[e]; i0 = e; }
            else if (v[e] > v1) { v1 = v[e]; i1 = e; }
        }
        const int b0 = 2 * r, b1 = 2 * r + 1;
        ls_beamw[b0] = v0;  ls_beamw[b1] = v1;
        if (hw == 0) {
            out[OUT_BS + b0] = v0;          out[OUT_BS + b1] = v1;
            out[OUT_ER + b0] = (float)i0;   out[OUT_ER + b1] = (float)i1;
            out[OUT_BI + b0] = (float)b0;   out[OUT_BI + b1] = (float)b1;
            float imp[E];
            #pragma unroll
            for (int e = 0; e < E; ++e) {
                float t = v[e];
                #pragma unroll
                for (int off = 1; off < 64; off <<= 1) t += __shfl_xor(t, off, 64);
                imp[e] = t;
            }
            if (r == 0) {
                float tot = 0.f;
                #pragma unroll
                for (int e = 0; e < E; ++e) tot += imp[e];
                const float mean = tot / E;
                float var = 0.f;
                #pragma unroll
                for (int e = 0; e < E; ++e) { float d = imp[e] - mean; var += d * d; }
                var /= (E - 1);
                out[OUT_IL] = var / (mean * mean);
            }
        }
        unsigned long long m0[E], m1[E];
        #pragma unroll
        for (int e = 0; e < E; ++e) {
            m0[e] = __ballot(i0 == e);
            m1[e] = __ballot(i1 == e);
        }
        int cnt[E], off[E];
        int a0 = 0;
        #pragma unroll
        for (int e = 0; e < E; ++e) {
            cnt[e] = __popcll(m0[e]) + __popcll(m1[e]);
            off[e] = a0; a0 += cnt[e];
        }
        const unsigned long long below = (r == 0) ? 0ull : ((1ull << r) - 1ull);
        const unsigned long long incl  = below | (1ull << r);
        const int pos0 = __popcll(m0[i0] & below) + __popcll(m1[i0] & below);
        const int pos1 = __popcll(m0[i1] & incl)  + __popcll(m1[i1] & below);
        ls_sortb[off[i0] + pos0] = b0;
        ls_sortb[off[i1] + pos1] = b1;
        if (r == 0) {
            int tiles[E];
            int used[NT8MAX];
            for (int t = 0; t < NT8MAX; ++t) used[t] = 0;
            #pragma unroll
            for (int e = 0; e < E; ++e) tiles[e] = (cnt[e] + 7) >> 3;
            #pragma unroll
            for (int e = 0; e < E; ++e) {
                const int k = tiles[e] < 3 ? tiles[e] : 3;
                for (int i = 0; i < k; ++i) {
                    const int sl = 3 * e + i;
                    ls_t8e[sl] = e; ls_t8b[sl] = off[e] + 8 * i;
                    const int rem = cnt[e] - 8 * i;
                    ls_t8c[sl] = rem < 8 ? rem : 8;
                    used[sl] = 1;
                }
            }
            int fs[NT8MAX]; int nf = 0;
            for (int round = 0; round < 3; ++round)
                for (int c = 0; c < E; ++c) {
                    const int sl = 3 * c + round;
                    if (!used[sl]) fs[nf++] = sl;
                }
            int fp = 0;
            for (int e = 0; e < E; ++e)
                for (int i = 3; i < tiles[e]; ++i) {
                    const int sl = fs[fp++];
                    ls_t8e[sl] = e; ls_t8b[sl] = off[e] + 8 * i;
                    const int rem = cnt[e] - 8 * i;
                    ls_t8c[sl] = rem < 8 ? rem : 8;
                    used[sl] = 1;
                }
            for (int t = 0; t < NT8MAX; ++t) if (!used[t]) ls_t8c[t] = 0;
        }
    }
    __syncthreads();   // tables visible to all 4 waves

    // ---- Phase 2: GEMM1 + GELU (24 tiles x 24 strips, K=768) ----
    gemm_body<H, true, 1, 24>(hw, x_bf, NB, w1, DFF, b1,
                              ls_sortb, ls_t8e, ls_t8b, ls_t8c, ls_beamw,
                              (void*)h_bf, sA, sB);

    grid.sync();   // h_bf visible everywhere

    // ---- Phase 3: GEMM2 + scale (24 tiles x 6 strips x 4 k-slices) ----
    gemm_body<DFF, false, 4, 6>(hw, h_bf, 1, w2, H, b2,
                                ls_sortb, ls_t8e, ls_t8b, ls_t8c, ls_beamw,
                                (void*)out, sA, sB);
}

// ---------------------------------------------------------------------------
// Fallback path (R5-equivalent separate kernels), used only if cooperative
// launch is unavailable.
// ---------------------------------------------------------------------------
__global__ __launch_bounds__(256) void gate_conv_kernel(
    const float* __restrict__ x, const float* __restrict__ gate_w,
    ushort* __restrict__ xb, float* __restrict__ logits_part)
{
    __shared__ float part[4][E];
    const int chunk = blockIdx.x, b = blockIdx.y;
    const int tid = threadIdx.x, wv = tid >> 6, lane = tid & 63;
    const int c = chunk * 256 + tid;
    const float* xp = x + (size_t)b * T * H + c;
    ushort* xo = xb + (size_t)b * T * H + c;
    float s = 0.f;
    #pragma unroll
    for (int t = 0; t < T; t += 2) {
        const float f0 = xp[t * H];
        const float f1 = xp[(t + 1) * H];
        s += f0; s += f1;
        __hip_bfloat162 t2 = __float22bfloat162_rn(make_float2(f0, f1));
        const unsigned u = *(const unsigned*)&t2;
        xo[t * H]       = (ushort)(u & 0xffff);
        xo[(t + 1) * H] = (ushort)(u >> 16);
    }
    const float avg = s * (1.0f / T);
    #pragma unroll
    for (int e = 0; e < E; ++e) {
        float p = avg * gate_w[e * H + c];
        #pragma unroll
        for (int off = 32; off; off >>= 1) p += __shfl_down(p, off, 64);
        if (lane == 0) part[wv][e] = p;
    }
    __syncthreads();
    if (tid < E) {
        float t = part[0][tid] + part[1][tid] + part[2][tid] + part[3][tid];
        logits_part[chunk * 512 + b * E + tid] = t;
    }
}

__global__ __launch_bounds__(64) void gating_kernel(
    const float* __restrict__ logits_part, float* __restrict__ beam_w,
    int* __restrict__ sortb, int* __restrict__ t8e, int* __restrict__ t8b,
    int* __restrict__ t8c, float* __restrict__ dout)
{
    const int r = threadIdx.x;
    float v[E];
    float mx = -1e30f;
    #pragma unroll
    for (int e = 0; e < E; ++e) {
        v[e] = logits_part[r * E + e] + logits_part[512 + r * E + e]
             + logits_part[1024 + r * E + e];
        mx = fmaxf(mx, v[e]);
    }
    float s = 0.f;
    #pragma unroll
    for (int e = 0; e < E; ++e) { v[e] = expf(v[e] - mx); s += v[e]; }
    const float inv = 1.0f / s;
    #pragma unroll
    for (int e = 0; e < E; ++e) v[e] *= inv;
    float v0 = -1.f, v1 = -1.f; int i0 = 0, i1 = 0;
    #pragma unroll
    for (int e = 0; e < E; ++e) {
        if (v[e] > v0)      { v1 = v0; i1 = i0; v0 = v[e]; i0 = e; }
        else if (v[e] > v1) { v1 = v[e]; i1 = e; }
    }
    const int b0 = 2 * r, b1 = 2 * r + 1;
    dout[OUT_BS + b0] = v0;          dout[OUT_BS + b1] = v1;
    dout[OUT_ER + b0] = (float)i0;   dout[OUT_ER + b1] = (float)i1;
    dout[OUT_BI + b0] = (float)b0;   dout[OUT_BI + b1] = (float)b1;
    beam_w[b0] = v0;  beam_w[b1] = v1;
    float imp[E];
    #pragma unroll
    for (int e = 0; e < E; ++e) {
        float t = v[e];
        #pragma unroll
        for (int off = 1; off < 64; off <<= 1) t += __shfl_xor(t, off, 64);
        imp[e] = t;
    }
    if (r == 0) {
        float tot = 0.f;
        #pragma unroll
        for (int e = 0; e < E; ++e) tot += imp[e];
        const float mean = tot / E;
        float var = 0.f;
        #pragma unroll
        for (int e = 0; e < E; ++e) { float d = imp[e] - mean; var += d * d; }
        var /= (E - 1);
        dout[OUT_IL] = var / (mean * mean);
    }
    unsigned long long m0[E], m1[E];
    #pragma unroll
    for (int e = 0; e < E; ++e) {
        m0[e] = __ballot(i0 == e);
        m1[e] = __ballot(i1 == e);
    }
    int cnt[E], off[E];
    int a0 = 0;
    #pragma unroll
    for (int e = 0; e < E; ++e) {
        cnt[e] = __popcll(m0[e]) + __popcll(m1[e]);
        off[e] = a0; a0 += cnt[e];
    }
    const unsigned long long below = (r == 0) ? 0ull : ((1ull << r) - 1ull);
    const unsigned long long incl  = below | (1ull << r);
    const int pos0 = __popcll(m0[i0] & below) + __popcll(m1[i0] & below);
    const int pos1 = __popcll(m0[i1] & incl)  + __popcll(m1[i1] & below);
    sortb[off[i0] + pos0] = b0;
    sortb[off[i1] + pos1] = b1;
    if (r == 0) {
        int tiles[E];
        int used[NT8MAX];
        for (int t = 0; t < NT8MAX; ++t) used[t] = 0;
        #pragma unroll
        for (int e = 0; e < E; ++e) tiles[e] = (cnt[e] + 7) >> 3;
        #pragma unroll
        for (int e = 0; e < E; ++e) {
            const int k = tiles[e] < 3 ? tiles[e] : 3;
            for (int i = 0; i < k; ++i) {
                const int sl = 3 * e + i;
                t8e[sl] = e; t8b[sl] = off[e] + 8 * i;
                const int rem = cnt[e] - 8 * i;
                t8c[sl] = rem < 8 ? rem : 8;
                used[sl] = 1;
            }
        }
        int fs[NT8MAX]; int nf = 0;
        for (int round = 0; round < 3; ++round)
            for (int c = 0; c < E; ++c) {
                const int sl = 3 * c + round;
                if (!used[sl]) fs[nf++] = sl;
            }
        int fp = 0;
        for (int e = 0; e < E; ++e)
            for (int i = 3; i < tiles[e]; ++i) {
                const int sl = fs[fp++];
                t8e[sl] = e; t8b[sl] = off[e] + 8 * i;
                const int rem = cnt[e] - 8 * i;
                t8c[sl] = rem < 8 ? rem : 8;
                used[sl] = 1;
            }
        for (int t = 0; t < NT8MAX; ++t) if (!used[t]) t8c[t] = 0;
    }
}

template <int KTOT, bool DO_GELU, int NSLICE, int NX>
__global__ __launch_bounds__(256, 2) void moe_ffn_direct(
    const ushort* __restrict__ Abf, int a_div,
    const float* __restrict__ Wf32, int w_rows,
    const float* __restrict__ biasb,
    const int* __restrict__ sortb, const int* __restrict__ t8e,
    const int* __restrict__ t8b, const int* __restrict__ t8c,
    const float* __restrict__ beam_w,
    void* __restrict__ Obase)
{
    __shared__ __align__(16) ushort sA[2][256 * 32];
    __shared__ __align__(16) ushort sB[2][128 * 32];
    const int hw = blockIdx.y * gridDim.x + blockIdx.x;
    gemm_body<KTOT, DO_GELU, NSLICE, NX>(hw, Abf, a_div, Wf32, w_rows, biasb,
                                         sortb, t8e, t8b, t8c, beam_w, Obase,
                                         sA, sB);
}

extern "C" void kernel_launch(void* const* d_in, const int* in_sizes, int n_in,
                              void* d_out, int out_size, void* d_ws, size_t ws_size,
                              hipStream_t stream)
{
    const float* x      = (const float*)d_in[0];
    const float* gate_w = (const float*)d_in[1];
    const float* w1     = (const float*)d_in[2];
    const float* b1     = (const float*)d_in[3];
    const float* w2     = (const float*)d_in[4];
    const float* b2     = (const float*)d_in[5];
    float* out = (float*)d_out;
    float* ws  = (float*)d_ws;

    float*  logits = ws + WS_LOGITS;
    float*  beam_w = ws + WS_BEAMW;
    int*    sortb  = (int*)(ws + WS_SORT);
    int*    t8e    = (int*)(ws + WS_T8E);
    int*    t8b    = (int*)(ws + WS_T8B);
    int*    t8c    = (int*)(ws + WS_T8C);
    ushort* x_bf   = (ushort*)(ws + WS_XBF);
    ushort* h_bf   = (ushort*)(ws + WS_HBF);

    // ---- fused cooperative path ----
    void* kargs[] = {
        (void*)&x, (void*)&gate_w, (void*)&w1, (void*)&b1, (void*)&w2,
        (void*)&b2, (void*)&out, (void*)&x_bf, (void*)&h_bf, (void*)&logits
    };
    hipError_t err = hipLaunchCooperativeKernel(
        (const void*)fused_moe, dim3(NBLK), dim3(256), kargs, 0, stream);
    if (err == hipSuccess) return;

    // ---- fallback: R5-equivalent multi-dispatch path ----
    hipMemsetAsync(out, 0, (size_t)NBEAM * T * H * sizeof(float), stream);
    gate_conv_kernel<<<dim3(3, Bsz), 256, 0, stream>>>(x, gate_w, x_bf, logits);
    gating_kernel<<<1, 64, 0, stream>>>(logits, beam_w, sortb, t8e, t8b, t8c, out);
    moe_ffn_direct<H, true, 1, 24><<<dim3(24, 24), 256, 0, stream>>>(
        x_bf, NB, w1, DFF, b1, sortb, t8e, t8b, t8c, beam_w, (void*)h_bf);
    moe_ffn_direct<DFF, false, 4, 6><<<dim3(6, 96), 256, 0, stream>>>(
        h_bf, 1, w2, H, b2, sortb, t8e, t8b, t8c, beam_w, out);
}